// Round 18
// baseline (316.098 us; speedup 1.0000x reference)
//
#include <hip/hip_runtime.h>

typedef __attribute__((ext_vector_type(8))) short bf16x8;
typedef __attribute__((ext_vector_type(4))) float f32x4;

constexpr int B  = 16;
constexpr int H  = 64;
constexpr int W  = 64;
constexpr int C  = 256;
constexpr int NH = 8;
constexpr int KD = 32;
constexpr float SCALE = 0.17677669529663687f; // 32^-0.5
constexpr int M_TOT = B * H * W;              // 65536
constexpr size_t NEL = (size_t)B * H * W * C; // 16777216

__device__ __forceinline__ unsigned short f2bf(float f) {
    union { float f; unsigned int u; } x; x.f = f;
    unsigned int u = x.u;
    unsigned int r = (u + 0x7fffu + ((u >> 16) & 1u)) >> 16;
    return (unsigned short)r;
}
__device__ __forceinline__ float bf2f(unsigned short s) {
    union { unsigned int u; float f; } x; x.u = ((unsigned int)s) << 16; return x.f;
}
__device__ __forceinline__ float bf_lo(unsigned int u) {
    union { unsigned int u; float f; } x; x.u = u << 16; return x.f;
}
__device__ __forceinline__ float bf_hi(unsigned int u) {
    union { unsigned int u; float f; } x; x.u = u & 0xffff0000u; return x.f;
}
__device__ __forceinline__ unsigned int pack2(float a, float b) {
    return (unsigned int)f2bf(a) | ((unsigned int)f2bf(b) << 16);
}
__device__ __forceinline__ void cvt8(uint4 rv, float* f) {
    f[0] = bf_lo(rv.x); f[1] = bf_hi(rv.x); f[2] = bf_lo(rv.y); f[3] = bf_hi(rv.y);
    f[4] = bf_lo(rv.z); f[5] = bf_hi(rv.z); f[6] = bf_lo(rv.w); f[7] = bf_hi(rv.w);
}
// LDS chunk swizzle (write-side + read-side, value-consistent)
__device__ __forceinline__ int swz(int row, int kp8) {
    return row * 32 + (kp8 ^ (((row >> 2) & 3) << 3));
}

// ---------------------------------------------------------------------------
// prep (merged): bid < 8192 -> x fp32->bf16; bid >= 8192 -> weight transpose
// ---------------------------------------------------------------------------
__global__ __launch_bounds__(256) void prep_all(
    const float* __restrict__ x, unsigned short* __restrict__ x16,
    const float* __restrict__ Wq, const float* __restrict__ Wk,
    const float* __restrict__ Wv, const float* __restrict__ Wo,
    unsigned short* __restrict__ wdst)
{
    int bid = blockIdx.x;
    if (bid < 8192) {
        size_t i8 = ((size_t)bid * 256 + threadIdx.x) * 8;
        float4 f0 = *(const float4*)(x + i8);
        float4 f1 = *(const float4*)(x + i8 + 4);
        uint4 o;
        o.x = pack2(f0.x, f0.y); o.y = pack2(f0.z, f0.w);
        o.z = pack2(f1.x, f1.y); o.w = pack2(f1.z, f1.w);
        *(uint4*)(x16 + i8) = o;
    } else {
        int tidg = (bid - 8192) * 256 + threadIdx.x;   // 0..32767
        int mat = tidg >> 13;
        int lt  = tidg & 8191;
        int n = lt >> 5, k0 = (lt & 31) << 3;
        const float* __restrict__ src = (mat == 0) ? Wq : (mat == 1) ? Wk : (mat == 2) ? Wv : Wo;
        unsigned int p[4];
#pragma unroll
        for (int j = 0; j < 4; ++j) {
            float a  = src[(size_t)(k0 + 2 * j) * 256 + n];
            float b2 = src[(size_t)(k0 + 2 * j + 1) * 256 + n];
            p[j] = pack2(a, b2);
        }
        uint4 o = {p[0], p[1], p[2], p[3]};
        *(uint4*)(wdst + ((size_t)mat * 65536) + (size_t)n * 256 + k0) = o;
    }
}

// ---------------------------------------------------------------------------
// Kernel 1: fused QKV MFMA GEMM (reg-staged LDS, R12 structure, bf16 x16 in).
// Swapped MFMA: C[row->n][col->m]. y 0..3 = q,k halves; y 4..5 = v.
// ---------------------------------------------------------------------------
__global__ __launch_bounds__(256) void qkv_mfma(
    const unsigned short* __restrict__ x16, const unsigned short* __restrict__ Wt16,
    const float* __restrict__ bq, const float* __restrict__ bk, const float* __restrict__ bv,
    const float* __restrict__ sin_t, const float* __restrict__ cos_t,
    unsigned short* __restrict__ qr, unsigned short* __restrict__ kr,
    unsigned short* __restrict__ v16)
{
    __shared__ __align__(16) unsigned short As[128 * 32];
    __shared__ __align__(16) unsigned short Bs[128 * 32];

    const int t = threadIdx.x;
    const int lane = t & 63, wid = t >> 6;
    const int wr = wid >> 1, wc = wid & 1;
    const int m0 = blockIdx.x * 128;
    const int n0 = blockIdx.y * 128;          // Wt16 row base (0..640)
    const int matid = blockIdx.y >> 1;        // 0=q 1=k 2=v
    const int nb = n0 & 255;                  // within-matrix n base

    f32x4 acc[4][4];
#pragma unroll
    for (int i = 0; i < 4; ++i)
#pragma unroll
        for (int j = 0; j < 4; ++j)
#pragma unroll
            for (int q = 0; q < 4; ++q) acc[i][j][q] = 0.f;

    const int row_s = t >> 2;            // 0..63
    const int kp_s  = (t & 3) << 3;      // 0,8,16,24

    for (int ks = 0; ks < 8; ++ks) {
        const int k0 = ks * 32;
        const unsigned short* ap = x16 + (size_t)(m0 + row_s) * 256 + k0 + kp_s;
        uint4 a0 = *(const uint4*)ap;
        uint4 a1 = *(const uint4*)(ap + 64 * 256);
        const unsigned short* bp = Wt16 + (size_t)(n0 + row_s) * 256 + k0 + kp_s;
        uint4 b0 = *(const uint4*)bp;
        uint4 b1 = *(const uint4*)(bp + 64 * 256);

        __syncthreads();
        *(uint4*)(&As[swz(row_s,      kp_s)]) = a0;
        *(uint4*)(&As[swz(row_s + 64, kp_s)]) = a1;
        *(uint4*)(&Bs[swz(row_s,      kp_s)]) = b0;
        *(uint4*)(&Bs[swz(row_s + 64, kp_s)]) = b1;
        __syncthreads();

        bf16x8 af[4], bf[4];
        const int rsel = lane & 15, kg8 = (lane >> 4) << 3;
#pragma unroll
        for (int i = 0; i < 4; ++i)
            af[i] = *(const bf16x8*)(&As[swz(wr * 64 + i * 16 + rsel, kg8)]);
#pragma unroll
        for (int j = 0; j < 4; ++j)
            bf[j] = *(const bf16x8*)(&Bs[swz(wc * 64 + j * 16 + rsel, kg8)]);
        // swapped: C[row->n][col->m]
#pragma unroll
        for (int i = 0; i < 4; ++i)
#pragma unroll
            for (int j = 0; j < 4; ++j)
                acc[i][j] = __builtin_amdgcn_mfma_f32_16x16x32_bf16(bf[j], af[i], acc[i][j], 0, 0, 0);
    }

    const int col_l = lane & 15, rowg = (lane >> 4) << 2;
    if (matid == 2) {
        // v: lane holds 4 consecutive n at row m -> ushort4 store
#pragma unroll
        for (int i = 0; i < 4; ++i) {
            const int m = m0 + wr * 64 + i * 16 + col_l;
#pragma unroll
            for (int j = 0; j < 4; ++j) {
                const int nn = nb + wc * 64 + j * 16 + rowg;
                float4 bias4 = *(const float4*)(bv + nn);
                ushort4 o;
                o.x = f2bf(acc[i][j][0] + bias4.x);
                o.y = f2bf(acc[i][j][1] + bias4.y);
                o.z = f2bf(acc[i][j][2] + bias4.z);
                o.w = f2bf(acc[i][j][3] + bias4.w);
                *(ushort4*)(v16 + (size_t)m * 256 + nn) = o;
            }
        }
    } else {
        // q/k: lane holds 4 consecutive d -> in-lane rotary, 8B stores
        const float sc = matid ? SCALE : 1.0f;
        const float* __restrict__ bias = matid ? bk : bq;
        unsigned short* __restrict__ dst = matid ? kr : qr;
#pragma unroll
        for (int i = 0; i < 4; ++i) {
            const int m = m0 + wr * 64 + i * 16 + col_l;
            const int bb = m >> 12, hh = (m >> 6) & 63, ww = m & 63;
            const size_t pixbase = ((size_t)hh * 64 + ww) * 32;
#pragma unroll
            for (int j = 0; j < 4; ++j) {
                const int n = nb + wc * 64 + j * 16 + rowg;  // 4 consecutive n
                const int nh = n >> 5, db = n & 31;
                float4 bias4 = *(const float4*)(bias + n);
                float4 cs4 = *(const float4*)(cos_t + pixbase + db);
                float4 sn4 = *(const float4*)(sin_t + pixbase + db);
                float v0 = (acc[i][j][0] + bias4.x) * sc;
                float v1 = (acc[i][j][1] + bias4.y) * sc;
                float v2 = (acc[i][j][2] + bias4.z) * sc;
                float v3 = (acc[i][j][3] + bias4.w) * sc;
                ushort4 o;
                o.x = f2bf(v0 * cs4.x - v1 * sn4.x);
                o.y = f2bf(v1 * cs4.y + v0 * sn4.y);
                o.z = f2bf(v2 * cs4.z - v3 * sn4.z);
                o.w = f2bf(v3 * cs4.w + v2 * sn4.w);
                *(ushort4*)(dst + ((((size_t)bb * 8 + nh) * 64 + hh) * 64 + ww) * 32 + db) = o;
            }
        }
    }
}

// ---------------------------------------------------------------------------
// Kernel 2: 5x5 depthwise conv (lepe), LDS-staged.
// Block = (b, h, c-quarter): stage 5 rows x 64 w x 64 c bf16 in LDS (46KB).
// Thread: cg = t&7 (8 channels), wpair = t>>3 -> outputs w = 2*wpair, 2*wpair+1.
// ---------------------------------------------------------------------------
__global__ __launch_bounds__(256) void conv_lds(
    const unsigned short* __restrict__ v, const float* __restrict__ cw,
    const float* __restrict__ cb, unsigned short* __restrict__ lepe)
{
    __shared__ __align__(16) unsigned short vs[5][64][72];  // [dy][w][c(64)+pad]

    const int bid = blockIdx.x;
    const int cq = bid & 3;
    const int h  = (bid >> 2) & 63;
    const int b  = bid >> 8;
    const int t  = threadIdx.x;
    const int cg = t & 7;          // channel octet within quarter
    const int c8 = cg << 3;        // 0..56
    const int cbase = cq * 64 + c8;
    const int wpair = t >> 3;      // 0..31
    const int w0 = wpair << 1;

    // stage 5 rows (zero-padded at h edges)
    for (int i = t; i < 2560; i += 256) {
        const int scg = i & 7, sw = (i >> 3) & 63, sdy = i >> 9;
        const int yy = h + sdy - 2;
        uint4 val = {0u, 0u, 0u, 0u};
        if (yy >= 0 && yy < 64)
            val = *(const uint4*)(v + ((size_t)(b * 64 + yy) * 64 + sw) * 256 + cq * 64 + scg * 8);
        *(uint4*)(&vs[sdy][sw][scg * 8]) = val;
    }
    __syncthreads();

    float acc[2][8];
    {
        float4 cb0 = *(const float4*)(cb + cbase);
        float4 cb1 = *(const float4*)(cb + cbase + 4);
#pragma unroll
        for (int wi = 0; wi < 2; ++wi) {
            acc[wi][0] = cb0.x; acc[wi][1] = cb0.y; acc[wi][2] = cb0.z; acc[wi][3] = cb0.w;
            acc[wi][4] = cb1.x; acc[wi][5] = cb1.y; acc[wi][6] = cb1.z; acc[wi][7] = cb1.w;
        }
    }

#pragma unroll
    for (int dy = 0; dy < 5; ++dy) {
        float rowf[6][8];
#pragma unroll
        for (int e = 0; e < 6; ++e) {
            const int xx = w0 + e - 2;
            if (xx < 0 || xx >= 64) {
#pragma unroll
                for (int q = 0; q < 8; ++q) rowf[e][q] = 0.f;
            } else {
                uint4 rv = *(const uint4*)(&vs[dy][xx][c8]);
                cvt8(rv, rowf[e]);
            }
        }
#pragma unroll
        for (int dx = 0; dx < 5; ++dx) {
            const float* wp = cw + (dy * 5 + dx) * 256 + cbase;
            float4 wv0 = *(const float4*)wp;
            float4 wv1 = *(const float4*)(wp + 4);
#pragma unroll
            for (int wi = 0; wi < 2; ++wi) {
                const float* rf = rowf[dx + wi];
                acc[wi][0] += rf[0] * wv0.x; acc[wi][1] += rf[1] * wv0.y;
                acc[wi][2] += rf[2] * wv0.z; acc[wi][3] += rf[3] * wv0.w;
                acc[wi][4] += rf[4] * wv1.x; acc[wi][5] += rf[5] * wv1.y;
                acc[wi][6] += rf[6] * wv1.z; acc[wi][7] += rf[7] * wv1.w;
            }
        }
    }

#pragma unroll
    for (int wi = 0; wi < 2; ++wi) {
        uint4 ov;
        ov.x = pack2(acc[wi][0], acc[wi][1]); ov.y = pack2(acc[wi][2], acc[wi][3]);
        ov.z = pack2(acc[wi][4], acc[wi][5]); ov.w = pack2(acc[wi][6], acc[wi][7]);
        *(uint4*)(lepe + ((size_t)(b * 64 + h) * 64 + w0 + wi) * 256 + cbase) = ov;
    }
}

// ---------------------------------------------------------------------------
// Kernel 3/4: MFMA attention along one axis. One block per (b,pos,nh).
// ---------------------------------------------------------------------------
template <int AXIS>
__global__ __launch_bounds__(256) void attn_mfma(
    const unsigned short* __restrict__ qr, const unsigned short* __restrict__ kr,
    const unsigned short* __restrict__ vin, const float* __restrict__ mask,
    const unsigned short* __restrict__ addin, unsigned short* __restrict__ outp)
{
    __shared__ __align__(16) short qs[64 * 40];
    __shared__ __align__(16) short ks[64 * 40];
    __shared__ __align__(16) short vt[32 * 72];
    __shared__ __align__(16) short P [64 * 72];

    const int t    = threadIdx.x;
    const int lane = t & 63, wv = t >> 6;
    const int bid  = blockIdx.x;
    const int nh   = bid & 7;
    const int pos  = (bid >> 3) & 63;
    const int b    = bid >> 9;

    size_t qbase, vbase;
    int qstride, vstride;
    if (AXIS == 0) {
        qbase   = ((size_t)(b * 8 + nh) * 64 + pos) * 2048;
        qstride = 32;
        vbase   = ((size_t)(b * 64 + pos) * 64) * 256 + nh * 32;
        vstride = 256;
    } else {
        qbase   = ((size_t)(b * 8 + nh) * 64) * 2048 + pos * 32;
        qstride = 2048;
        vbase   = ((size_t)b * 64 * 64) * 256 + pos * 256 + nh * 32;
        vstride = 16384;
    }

    {
        int row = t >> 2, c8 = (t & 3) << 3;
        uint4 rq = *(const uint4*)(qr + qbase + (size_t)row * qstride + c8);
        *(uint4*)(&qs[row * 40 + c8]) = rq;
        uint4 rk = *(const uint4*)(kr + qbase + (size_t)row * qstride + c8);
        *(uint4*)(&ks[row * 40 + c8]) = rk;
        uint4 rv = *(const uint4*)(vin + vbase + (size_t)row * vstride + c8);
        const unsigned short* pv = (const unsigned short*)&rv;
#pragma unroll
        for (int j = 0; j < 8; ++j) vt[(c8 + j) * 72 + row] = pv[j];
    }
    __syncthreads();

    const int rsel = lane & 15;
    const int kg   = (lane >> 4) << 3;
    const int rowg = (lane >> 4) << 2;

    bf16x8 aq = *(const bf16x8*)(&qs[(wv * 16 + rsel) * 40 + kg]);
    f32x4 s[4];
    __builtin_amdgcn_s_setprio(1);
#pragma unroll
    for (int j = 0; j < 4; ++j) {
        f32x4 z = {0.f, 0.f, 0.f, 0.f};
        bf16x8 bk8 = *(const bf16x8*)(&ks[(j * 16 + rsel) * 40 + kg]);
        s[j] = __builtin_amdgcn_mfma_f32_16x16x32_bf16(aq, bk8, z, 0, 0, 0);
    }
    __builtin_amdgcn_s_setprio(0);

    const float* __restrict__ mrow = mask + (size_t)nh * 4096;
#pragma unroll
    for (int r = 0; r < 4; ++r) {
        const int grow = wv * 16 + rowg + r;
#pragma unroll
        for (int j = 0; j < 4; ++j)
            s[j][r] += mrow[grow * 64 + j * 16 + rsel];
        float mx = fmaxf(fmaxf(s[0][r], s[1][r]), fmaxf(s[2][r], s[3][r]));
        mx = fmaxf(mx, __shfl_xor(mx, 1));
        mx = fmaxf(mx, __shfl_xor(mx, 2));
        mx = fmaxf(mx, __shfl_xor(mx, 4));
        mx = fmaxf(mx, __shfl_xor(mx, 8));
        float e0 = __expf(s[0][r] - mx), e1 = __expf(s[1][r] - mx);
        float e2 = __expf(s[2][r] - mx), e3 = __expf(s[3][r] - mx);
        float sum = e0 + e1 + e2 + e3;
        sum += __shfl_xor(sum, 1);
        sum += __shfl_xor(sum, 2);
        sum += __shfl_xor(sum, 4);
        sum += __shfl_xor(sum, 8);
        float inv = 1.0f / sum;
        P[grow * 72 +      rsel] = f2bf(e0 * inv);
        P[grow * 72 + 16 + rsel] = f2bf(e1 * inv);
        P[grow * 72 + 32 + rsel] = f2bf(e2 * inv);
        P[grow * 72 + 48 + rsel] = f2bf(e3 * inv);
    }
    __syncthreads();

    f32x4 o[2];
#pragma unroll
    for (int n = 0; n < 2; ++n)
#pragma unroll
        for (int q = 0; q < 4; ++q) o[n][q] = 0.f;
    __builtin_amdgcn_s_setprio(1);
#pragma unroll
    for (int kk = 0; kk < 2; ++kk) {
        bf16x8 ap = *(const bf16x8*)(&P[(wv * 16 + rsel) * 72 + kk * 32 + kg]);
#pragma unroll
        for (int n = 0; n < 2; ++n) {
            bf16x8 bv8 = *(const bf16x8*)(&vt[(n * 16 + rsel) * 72 + kk * 32 + kg]);
            o[n] = __builtin_amdgcn_mfma_f32_16x16x32_bf16(ap, bv8, o[n], 0, 0, 0);
        }
    }
    __builtin_amdgcn_s_setprio(0);

#pragma unroll
    for (int n = 0; n < 2; ++n)
#pragma unroll
        for (int r = 0; r < 4; ++r) {
            const int grow = wv * 16 + rowg + r;
            size_t oidx = vbase + (size_t)grow * vstride + n * 16 + rsel;
            float val = o[n][r];
            if (AXIS == 1) val += bf2f(addin[oidx]);
            outp[oidx] = f2bf(val);
        }
}

// ---------------------------------------------------------------------------
// Kernel 5: output MFMA GEMM (reg-staged, R12 structure): y16 @ Wot16^T + bo
// ---------------------------------------------------------------------------
__global__ __launch_bounds__(256) void gemm_out_mfma(
    const unsigned short* __restrict__ y16, const unsigned short* __restrict__ Wot16,
    const float* __restrict__ bo, float* __restrict__ out)
{
    __shared__ __align__(16) unsigned short As[128 * 32];
    __shared__ __align__(16) unsigned short Bs[128 * 32];

    const int t = threadIdx.x;
    const int lane = t & 63, wid = t >> 6;
    const int wr = wid >> 1, wc = wid & 1;
    const int m0 = blockIdx.x * 128;
    const int n0 = blockIdx.y * 128;

    f32x4 acc[4][4];
#pragma unroll
    for (int i = 0; i < 4; ++i)
#pragma unroll
        for (int j = 0; j < 4; ++j)
#pragma unroll
            for (int q = 0; q < 4; ++q) acc[i][j][q] = 0.f;

    const int row_s = t >> 2;
    const int kp_s  = (t & 3) << 3;

    for (int ks = 0; ks < 8; ++ks) {
        const int k0 = ks * 32;
        const unsigned short* ap = y16 + (size_t)(m0 + row_s) * 256 + k0 + kp_s;
        uint4 a0 = *(const uint4*)ap;
        uint4 a1 = *(const uint4*)(ap + 64 * 256);
        const unsigned short* bp = Wot16 + (size_t)(n0 + row_s) * 256 + k0 + kp_s;
        uint4 b0 = *(const uint4*)bp;
        uint4 b1 = *(const uint4*)(bp + 64 * 256);

        __syncthreads();
        *(uint4*)(&As[swz(row_s,      kp_s)]) = a0;
        *(uint4*)(&As[swz(row_s + 64, kp_s)]) = a1;
        *(uint4*)(&Bs[swz(row_s,      kp_s)]) = b0;
        *(uint4*)(&Bs[swz(row_s + 64, kp_s)]) = b1;
        __syncthreads();

        bf16x8 af[4], bf[4];
        const int rsel = lane & 15, kg8 = (lane >> 4) << 3;
#pragma unroll
        for (int i = 0; i < 4; ++i)
            af[i] = *(const bf16x8*)(&As[swz(wr * 64 + i * 16 + rsel, kg8)]);
#pragma unroll
        for (int j = 0; j < 4; ++j)
            bf[j] = *(const bf16x8*)(&Bs[swz(wc * 64 + j * 16 + rsel, kg8)]);
#pragma unroll
        for (int i = 0; i < 4; ++i)
#pragma unroll
            for (int j = 0; j < 4; ++j)
                acc[i][j] = __builtin_amdgcn_mfma_f32_16x16x32_bf16(af[i], bf[j], acc[i][j], 0, 0, 0);
    }

    const int col_l = lane & 15, rowg = (lane >> 4) << 2;
#pragma unroll
    for (int i = 0; i < 4; ++i)
#pragma unroll
        for (int j = 0; j < 4; ++j) {
            int nn = n0 + wc * 64 + j * 16 + col_l;
            float bias = bo[nn];
#pragma unroll
            for (int r = 0; r < 4; ++r) {
                int m = m0 + wr * 64 + i * 16 + rowg + r;
                out[(size_t)m * 256 + nn] = acc[i][j][r] + bias;
            }
        }
}

// ---------------------------------------------------------------------------
extern "C" void kernel_launch(void* const* d_in, const int* in_sizes, int n_in,
                              void* d_out, int out_size, void* d_ws, size_t ws_size,
                              hipStream_t stream) {
    const float* x      = (const float*)d_in[0];
    const float* sin_t  = (const float*)d_in[1];
    const float* cos_t  = (const float*)d_in[2];
    const float* mask_h = (const float*)d_in[3];
    const float* mask_w = (const float*)d_in[4];
    const float* Wq     = (const float*)d_in[5];
    const float* bq     = (const float*)d_in[6];
    const float* Wk     = (const float*)d_in[7];
    const float* bk     = (const float*)d_in[8];
    const float* Wv     = (const float*)d_in[9];
    const float* bv     = (const float*)d_in[10];
    const float* conv_w = (const float*)d_in[11];
    const float* conv_b = (const float*)d_in[12];
    const float* Wo     = (const float*)d_in[13];
    const float* bo     = (const float*)d_in[14];

    // ws (bf16 buffers)
    unsigned short* ws    = (unsigned short*)d_ws;
    unsigned short* v16   = ws;              // (B,H,W,C)
    unsigned short* lepe16= v16 + NEL;       // (B,H,W,C)
    unsigned short* qr16  = lepe16 + NEL;    // (B,NH,H,W,KD)
    unsigned short* kr16  = qr16 + NEL;
    unsigned short* y16   = kr16 + NEL;      // (B,H,W,C)
    unsigned short* Wt16  = y16 + NEL;       // (768,256) n-major (+Wo after)
    unsigned short* Wot16 = Wt16 + 768 * 256;// (256,256) n-major

    // d_out scratch: lower half = vv16 (bf16), upper half = x16 (bf16).
    unsigned short* vv16 = (unsigned short*)d_out;
    unsigned short* x16  = (unsigned short*)d_out + NEL;

    prep_all<<<8192 + 128, 256, 0, stream>>>(x, x16, Wq, Wk, Wv, Wo, Wt16);

    qkv_mfma<<<dim3(M_TOT / 128, 6), 256, 0, stream>>>(
        x16, Wt16, bq, bk, bv, sin_t, cos_t, qr16, kr16, v16);

    conv_lds<<<B * H * 4, 256, 0, stream>>>(v16, conv_w, conv_b, lepe16);

    attn_mfma<0><<<B * H * NH, 256, 0, stream>>>(qr16, kr16, v16, mask_w, nullptr, vv16);

    attn_mfma<1><<<B * W * NH, 256, 0, stream>>>(qr16, kr16, vv16, mask_h, lepe16, y16);

    gemm_out_mfma<<<dim3(M_TOT / 128, 2), 256, 0, stream>>>(y16, Wot16, bo, (float*)d_out);
}

// Round 19
// 238.404 us; speedup vs baseline: 1.3259x; 1.3259x over previous
//
#include <hip/hip_runtime.h>

typedef __attribute__((ext_vector_type(8))) short bf16x8;
typedef __attribute__((ext_vector_type(4))) float f32x4;

constexpr int B  = 16;
constexpr int H  = 64;
constexpr int W  = 64;
constexpr int C  = 256;
constexpr int NH = 8;
constexpr int KD = 32;
constexpr float SCALE = 0.17677669529663687f; // 32^-0.5
constexpr int M_TOT = B * H * W;              // 65536
constexpr size_t NEL = (size_t)B * H * W * C; // 16777216

__device__ __forceinline__ unsigned short f2bf(float f) {
    union { float f; unsigned int u; } x; x.f = f;
    unsigned int u = x.u;
    unsigned int r = (u + 0x7fffu + ((u >> 16) & 1u)) >> 16;
    return (unsigned short)r;
}
__device__ __forceinline__ float bf2f(unsigned short s) {
    union { unsigned int u; float f; } x; x.u = ((unsigned int)s) << 16; return x.f;
}
__device__ __forceinline__ float bf_lo(unsigned int u) {
    union { unsigned int u; float f; } x; x.u = u << 16; return x.f;
}
__device__ __forceinline__ float bf_hi(unsigned int u) {
    union { unsigned int u; float f; } x; x.u = u & 0xffff0000u; return x.f;
}
__device__ __forceinline__ unsigned int pack2(float a, float b) {
    return (unsigned int)f2bf(a) | ((unsigned int)f2bf(b) << 16);
}
__device__ __forceinline__ void cvt8(uint4 rv, float* f) {
    f[0] = bf_lo(rv.x); f[1] = bf_hi(rv.x); f[2] = bf_lo(rv.y); f[3] = bf_hi(rv.y);
    f[4] = bf_lo(rv.z); f[5] = bf_hi(rv.z); f[6] = bf_lo(rv.w); f[7] = bf_hi(rv.w);
}
// LDS chunk swizzle (write-side + read-side, value-consistent)
__device__ __forceinline__ int swz(int row, int kp8) {
    return row * 32 + (kp8 ^ (((row >> 2) & 3) << 3));
}

// ---------------------------------------------------------------------------
// prep (merged): bid < 8192 -> x fp32->bf16; bid >= 8192 -> weight transpose
// ---------------------------------------------------------------------------
__global__ __launch_bounds__(256) void prep_all(
    const float* __restrict__ x, unsigned short* __restrict__ x16,
    const float* __restrict__ Wq, const float* __restrict__ Wk,
    const float* __restrict__ Wv, const float* __restrict__ Wo,
    unsigned short* __restrict__ wdst)
{
    int bid = blockIdx.x;
    if (bid < 8192) {
        size_t i8 = ((size_t)bid * 256 + threadIdx.x) * 8;
        float4 f0 = *(const float4*)(x + i8);
        float4 f1 = *(const float4*)(x + i8 + 4);
        uint4 o;
        o.x = pack2(f0.x, f0.y); o.y = pack2(f0.z, f0.w);
        o.z = pack2(f1.x, f1.y); o.w = pack2(f1.z, f1.w);
        *(uint4*)(x16 + i8) = o;
    } else {
        int tidg = (bid - 8192) * 256 + threadIdx.x;   // 0..32767
        int mat = tidg >> 13;
        int lt  = tidg & 8191;
        int n = lt >> 5, k0 = (lt & 31) << 3;
        const float* __restrict__ src = (mat == 0) ? Wq : (mat == 1) ? Wk : (mat == 2) ? Wv : Wo;
        unsigned int p[4];
#pragma unroll
        for (int j = 0; j < 4; ++j) {
            float a  = src[(size_t)(k0 + 2 * j) * 256 + n];
            float b2 = src[(size_t)(k0 + 2 * j + 1) * 256 + n];
            p[j] = pack2(a, b2);
        }
        uint4 o = {p[0], p[1], p[2], p[3]};
        *(uint4*)(wdst + ((size_t)mat * 65536) + (size_t)n * 256 + k0) = o;
    }
}

// ---------------------------------------------------------------------------
// Kernel 1: fused QKV MFMA GEMM (reg-staged LDS, bf16 x16 in).
// Swapped MFMA: C[row->n][col->m]. y 0..3 = q,k halves; y 4..5 = v.
// ---------------------------------------------------------------------------
__global__ __launch_bounds__(256) void qkv_mfma(
    const unsigned short* __restrict__ x16, const unsigned short* __restrict__ Wt16,
    const float* __restrict__ bq, const float* __restrict__ bk, const float* __restrict__ bv,
    const float* __restrict__ sin_t, const float* __restrict__ cos_t,
    unsigned short* __restrict__ qr, unsigned short* __restrict__ kr,
    unsigned short* __restrict__ v16)
{
    __shared__ __align__(16) unsigned short As[128 * 32];
    __shared__ __align__(16) unsigned short Bs[128 * 32];

    const int t = threadIdx.x;
    const int lane = t & 63, wid = t >> 6;
    const int wr = wid >> 1, wc = wid & 1;
    const int m0 = blockIdx.x * 128;
    const int n0 = blockIdx.y * 128;          // Wt16 row base (0..640)
    const int matid = blockIdx.y >> 1;        // 0=q 1=k 2=v
    const int nb = n0 & 255;                  // within-matrix n base

    f32x4 acc[4][4];
#pragma unroll
    for (int i = 0; i < 4; ++i)
#pragma unroll
        for (int j = 0; j < 4; ++j)
#pragma unroll
            for (int q = 0; q < 4; ++q) acc[i][j][q] = 0.f;

    const int row_s = t >> 2;            // 0..63
    const int kp_s  = (t & 3) << 3;      // 0,8,16,24

    for (int ks = 0; ks < 8; ++ks) {
        const int k0 = ks * 32;
        const unsigned short* ap = x16 + (size_t)(m0 + row_s) * 256 + k0 + kp_s;
        uint4 a0 = *(const uint4*)ap;
        uint4 a1 = *(const uint4*)(ap + 64 * 256);
        const unsigned short* bp = Wt16 + (size_t)(n0 + row_s) * 256 + k0 + kp_s;
        uint4 b0 = *(const uint4*)bp;
        uint4 b1 = *(const uint4*)(bp + 64 * 256);

        __syncthreads();
        *(uint4*)(&As[swz(row_s,      kp_s)]) = a0;
        *(uint4*)(&As[swz(row_s + 64, kp_s)]) = a1;
        *(uint4*)(&Bs[swz(row_s,      kp_s)]) = b0;
        *(uint4*)(&Bs[swz(row_s + 64, kp_s)]) = b1;
        __syncthreads();

        bf16x8 af[4], bf[4];
        const int rsel = lane & 15, kg8 = (lane >> 4) << 3;
#pragma unroll
        for (int i = 0; i < 4; ++i)
            af[i] = *(const bf16x8*)(&As[swz(wr * 64 + i * 16 + rsel, kg8)]);
#pragma unroll
        for (int j = 0; j < 4; ++j)
            bf[j] = *(const bf16x8*)(&Bs[swz(wc * 64 + j * 16 + rsel, kg8)]);
        // swapped: C[row->n][col->m]
#pragma unroll
        for (int i = 0; i < 4; ++i)
#pragma unroll
            for (int j = 0; j < 4; ++j)
                acc[i][j] = __builtin_amdgcn_mfma_f32_16x16x32_bf16(bf[j], af[i], acc[i][j], 0, 0, 0);
    }

    const int col_l = lane & 15, rowg = (lane >> 4) << 2;
    if (matid == 2) {
        // v: lane holds 4 consecutive n at row m -> ushort4 store
#pragma unroll
        for (int i = 0; i < 4; ++i) {
            const int m = m0 + wr * 64 + i * 16 + col_l;
#pragma unroll
            for (int j = 0; j < 4; ++j) {
                const int nn = nb + wc * 64 + j * 16 + rowg;
                float4 bias4 = *(const float4*)(bv + nn);
                ushort4 o;
                o.x = f2bf(acc[i][j][0] + bias4.x);
                o.y = f2bf(acc[i][j][1] + bias4.y);
                o.z = f2bf(acc[i][j][2] + bias4.z);
                o.w = f2bf(acc[i][j][3] + bias4.w);
                *(ushort4*)(v16 + (size_t)m * 256 + nn) = o;
            }
        }
    } else {
        // q/k: lane holds 4 consecutive d -> in-lane rotary, 8B stores
        const float sc = matid ? SCALE : 1.0f;
        const float* __restrict__ bias = matid ? bk : bq;
        unsigned short* __restrict__ dst = matid ? kr : qr;
#pragma unroll
        for (int i = 0; i < 4; ++i) {
            const int m = m0 + wr * 64 + i * 16 + col_l;
            const int bb = m >> 12, hh = (m >> 6) & 63, ww = m & 63;
            const size_t pixbase = ((size_t)hh * 64 + ww) * 32;
#pragma unroll
            for (int j = 0; j < 4; ++j) {
                const int n = nb + wc * 64 + j * 16 + rowg;  // 4 consecutive n
                const int nh = n >> 5, db = n & 31;
                float4 bias4 = *(const float4*)(bias + n);
                float4 cs4 = *(const float4*)(cos_t + pixbase + db);
                float4 sn4 = *(const float4*)(sin_t + pixbase + db);
                float v0 = (acc[i][j][0] + bias4.x) * sc;
                float v1 = (acc[i][j][1] + bias4.y) * sc;
                float v2 = (acc[i][j][2] + bias4.z) * sc;
                float v3 = (acc[i][j][3] + bias4.w) * sc;
                ushort4 o;
                o.x = f2bf(v0 * cs4.x - v1 * sn4.x);
                o.y = f2bf(v1 * cs4.y + v0 * sn4.y);
                o.z = f2bf(v2 * cs4.z - v3 * sn4.z);
                o.w = f2bf(v3 * cs4.w + v2 * sn4.w);
                *(ushort4*)(dst + ((((size_t)bb * 8 + nh) * 64 + hh) * 64 + ww) * 32 + db) = o;
            }
        }
    }
}

// ---------------------------------------------------------------------------
// Kernel 2: 5x5 depthwise conv (lepe), bf16 in/out.
// Each thread: 8 channels x 4 consecutive w. Row-register reuse across taps.
// ---------------------------------------------------------------------------
__global__ __launch_bounds__(256) void conv_kernel(
    const unsigned short* __restrict__ v, const float* __restrict__ cw,
    const float* __restrict__ cb, unsigned short* __restrict__ lepe)
{
    size_t tid = (size_t)blockIdx.x * 256 + threadIdx.x;   // 512K threads
    const int c8 = (int)(tid & 31) << 3;          // channel group of 8
    const int w0 = ((int)(tid >> 5) & 15) << 2;   // 0,4,..,60
    const int h  = (int)(tid >> 9) & 63;
    const int b  = (int)(tid >> 15);

    float acc[4][8];
    {
        float4 cb0 = *(const float4*)(cb + c8);
        float4 cb1 = *(const float4*)(cb + c8 + 4);
#pragma unroll
        for (int o = 0; o < 4; ++o) {
            acc[o][0] = cb0.x; acc[o][1] = cb0.y; acc[o][2] = cb0.z; acc[o][3] = cb0.w;
            acc[o][4] = cb1.x; acc[o][5] = cb1.y; acc[o][6] = cb1.z; acc[o][7] = cb1.w;
        }
    }

    const unsigned short* __restrict__ vb = v + (size_t)b * 4096 * 256 + c8;
#pragma unroll
    for (int dy = 0; dy < 5; ++dy) {
        const int yy = h + dy - 2;
        if (yy < 0 || yy >= 64) continue;
        float rowf[8][8];
#pragma unroll
        for (int j = 0; j < 8; ++j) {
            const int xx = w0 + j - 2;
            if (xx < 0 || xx >= 64) {
#pragma unroll
                for (int q = 0; q < 8; ++q) rowf[j][q] = 0.f;
            } else {
                uint4 rv = *(const uint4*)(vb + (size_t)(yy * 64 + xx) * 256);
                cvt8(rv, rowf[j]);
            }
        }
#pragma unroll
        for (int dx = 0; dx < 5; ++dx) {
            const float* wp = cw + (dy * 5 + dx) * 256 + c8;
            float4 wv0 = *(const float4*)wp;
            float4 wv1 = *(const float4*)(wp + 4);
#pragma unroll
            for (int o = 0; o < 4; ++o) {
                const float* rf = rowf[dx + o];
                acc[o][0] += rf[0] * wv0.x; acc[o][1] += rf[1] * wv0.y;
                acc[o][2] += rf[2] * wv0.z; acc[o][3] += rf[3] * wv0.w;
                acc[o][4] += rf[4] * wv1.x; acc[o][5] += rf[5] * wv1.y;
                acc[o][6] += rf[6] * wv1.z; acc[o][7] += rf[7] * wv1.w;
            }
        }
    }

    unsigned short* __restrict__ op = lepe + (((size_t)(b * 64 + h) * 64) + w0) * 256 + c8;
#pragma unroll
    for (int o = 0; o < 4; ++o) {
        uint4 ov;
        ov.x = pack2(acc[o][0], acc[o][1]); ov.y = pack2(acc[o][2], acc[o][3]);
        ov.z = pack2(acc[o][4], acc[o][5]); ov.w = pack2(acc[o][6], acc[o][7]);
        *(uint4*)(op + (size_t)o * 256) = ov;
    }
}

// ---------------------------------------------------------------------------
// Kernel 3/4: MFMA attention along one axis. One block per (b,pos,nh).
// ---------------------------------------------------------------------------
template <int AXIS>
__global__ __launch_bounds__(256) void attn_mfma(
    const unsigned short* __restrict__ qr, const unsigned short* __restrict__ kr,
    const unsigned short* __restrict__ vin, const float* __restrict__ mask,
    const unsigned short* __restrict__ addin, unsigned short* __restrict__ outp)
{
    __shared__ __align__(16) short qs[64 * 40];
    __shared__ __align__(16) short ks[64 * 40];
    __shared__ __align__(16) short vt[32 * 72];
    __shared__ __align__(16) short P [64 * 72];

    const int t    = threadIdx.x;
    const int lane = t & 63, wv = t >> 6;
    const int bid  = blockIdx.x;
    const int nh   = bid & 7;
    const int pos  = (bid >> 3) & 63;
    const int b    = bid >> 9;

    size_t qbase, vbase;
    int qstride, vstride;
    if (AXIS == 0) {
        qbase   = ((size_t)(b * 8 + nh) * 64 + pos) * 2048;
        qstride = 32;
        vbase   = ((size_t)(b * 64 + pos) * 64) * 256 + nh * 32;
        vstride = 256;
    } else {
        qbase   = ((size_t)(b * 8 + nh) * 64) * 2048 + pos * 32;
        qstride = 2048;
        vbase   = ((size_t)b * 64 * 64) * 256 + pos * 256 + nh * 32;
        vstride = 16384;
    }

    {
        int row = t >> 2, c8 = (t & 3) << 3;
        uint4 rq = *(const uint4*)(qr + qbase + (size_t)row * qstride + c8);
        *(uint4*)(&qs[row * 40 + c8]) = rq;
        uint4 rk = *(const uint4*)(kr + qbase + (size_t)row * qstride + c8);
        *(uint4*)(&ks[row * 40 + c8]) = rk;
        uint4 rv = *(const uint4*)(vin + vbase + (size_t)row * vstride + c8);
        const unsigned short* pv = (const unsigned short*)&rv;
#pragma unroll
        for (int j = 0; j < 8; ++j) vt[(c8 + j) * 72 + row] = pv[j];
    }
    __syncthreads();

    const int rsel = lane & 15;
    const int kg   = (lane >> 4) << 3;
    const int rowg = (lane >> 4) << 2;

    bf16x8 aq = *(const bf16x8*)(&qs[(wv * 16 + rsel) * 40 + kg]);
    f32x4 s[4];
#pragma unroll
    for (int j = 0; j < 4; ++j) {
        f32x4 z = {0.f, 0.f, 0.f, 0.f};
        bf16x8 bk8 = *(const bf16x8*)(&ks[(j * 16 + rsel) * 40 + kg]);
        s[j] = __builtin_amdgcn_mfma_f32_16x16x32_bf16(aq, bk8, z, 0, 0, 0);
    }

    const float* __restrict__ mrow = mask + (size_t)nh * 4096;
#pragma unroll
    for (int r = 0; r < 4; ++r) {
        const int grow = wv * 16 + rowg + r;
#pragma unroll
        for (int j = 0; j < 4; ++j)
            s[j][r] += mrow[grow * 64 + j * 16 + rsel];
        float mx = fmaxf(fmaxf(s[0][r], s[1][r]), fmaxf(s[2][r], s[3][r]));
        mx = fmaxf(mx, __shfl_xor(mx, 1));
        mx = fmaxf(mx, __shfl_xor(mx, 2));
        mx = fmaxf(mx, __shfl_xor(mx, 4));
        mx = fmaxf(mx, __shfl_xor(mx, 8));
        float e0 = __expf(s[0][r] - mx), e1 = __expf(s[1][r] - mx);
        float e2 = __expf(s[2][r] - mx), e3 = __expf(s[3][r] - mx);
        float sum = e0 + e1 + e2 + e3;
        sum += __shfl_xor(sum, 1);
        sum += __shfl_xor(sum, 2);
        sum += __shfl_xor(sum, 4);
        sum += __shfl_xor(sum, 8);
        float inv = 1.0f / sum;
        P[grow * 72 +      rsel] = f2bf(e0 * inv);
        P[grow * 72 + 16 + rsel] = f2bf(e1 * inv);
        P[grow * 72 + 32 + rsel] = f2bf(e2 * inv);
        P[grow * 72 + 48 + rsel] = f2bf(e3 * inv);
    }
    __syncthreads();

    f32x4 o[2];
#pragma unroll
    for (int n = 0; n < 2; ++n)
#pragma unroll
        for (int q = 0; q < 4; ++q) o[n][q] = 0.f;
#pragma unroll
    for (int kk = 0; kk < 2; ++kk) {
        bf16x8 ap = *(const bf16x8*)(&P[(wv * 16 + rsel) * 72 + kk * 32 + kg]);
#pragma unroll
        for (int n = 0; n < 2; ++n) {
            bf16x8 bv8 = *(const bf16x8*)(&vt[(n * 16 + rsel) * 72 + kk * 32 + kg]);
            o[n] = __builtin_amdgcn_mfma_f32_16x16x32_bf16(ap, bv8, o[n], 0, 0, 0);
        }
    }

#pragma unroll
    for (int n = 0; n < 2; ++n)
#pragma unroll
        for (int r = 0; r < 4; ++r) {
            const int grow = wv * 16 + rowg + r;
            size_t oidx = vbase + (size_t)grow * vstride + n * 16 + rsel;
            float val = o[n][r];
            if (AXIS == 1) val += bf2f(addin[oidx]);
            outp[oidx] = f2bf(val);
        }
}

// ---------------------------------------------------------------------------
// Kernel 5: output MFMA GEMM (reg-staged): y16 @ Wot16^T + bo -> fp32
// ---------------------------------------------------------------------------
__global__ __launch_bounds__(256) void gemm_out_mfma(
    const unsigned short* __restrict__ y16, const unsigned short* __restrict__ Wot16,
    const float* __restrict__ bo, float* __restrict__ out)
{
    __shared__ __align__(16) unsigned short As[128 * 32];
    __shared__ __align__(16) unsigned short Bs[128 * 32];

    const int t = threadIdx.x;
    const int lane = t & 63, wid = t >> 6;
    const int wr = wid >> 1, wc = wid & 1;
    const int m0 = blockIdx.x * 128;
    const int n0 = blockIdx.y * 128;

    f32x4 acc[4][4];
#pragma unroll
    for (int i = 0; i < 4; ++i)
#pragma unroll
        for (int j = 0; j < 4; ++j)
#pragma unroll
            for (int q = 0; q < 4; ++q) acc[i][j][q] = 0.f;

    const int row_s = t >> 2;
    const int kp_s  = (t & 3) << 3;

    for (int ks = 0; ks < 8; ++ks) {
        const int k0 = ks * 32;
        const unsigned short* ap = y16 + (size_t)(m0 + row_s) * 256 + k0 + kp_s;
        uint4 a0 = *(const uint4*)ap;
        uint4 a1 = *(const uint4*)(ap + 64 * 256);
        const unsigned short* bp = Wot16 + (size_t)(n0 + row_s) * 256 + k0 + kp_s;
        uint4 b0 = *(const uint4*)bp;
        uint4 b1 = *(const uint4*)(bp + 64 * 256);

        __syncthreads();
        *(uint4*)(&As[swz(row_s,      kp_s)]) = a0;
        *(uint4*)(&As[swz(row_s + 64, kp_s)]) = a1;
        *(uint4*)(&Bs[swz(row_s,      kp_s)]) = b0;
        *(uint4*)(&Bs[swz(row_s + 64, kp_s)]) = b1;
        __syncthreads();

        bf16x8 af[4], bf[4];
        const int rsel = lane & 15, kg8 = (lane >> 4) << 3;
#pragma unroll
        for (int i = 0; i < 4; ++i)
            af[i] = *(const bf16x8*)(&As[swz(wr * 64 + i * 16 + rsel, kg8)]);
#pragma unroll
        for (int j = 0; j < 4; ++j)
            bf[j] = *(const bf16x8*)(&Bs[swz(wc * 64 + j * 16 + rsel, kg8)]);
#pragma unroll
        for (int i = 0; i < 4; ++i)
#pragma unroll
            for (int j = 0; j < 4; ++j)
                acc[i][j] = __builtin_amdgcn_mfma_f32_16x16x32_bf16(af[i], bf[j], acc[i][j], 0, 0, 0);
    }

    const int col_l = lane & 15, rowg = (lane >> 4) << 2;
#pragma unroll
    for (int i = 0; i < 4; ++i)
#pragma unroll
        for (int j = 0; j < 4; ++j) {
            int nn = n0 + wc * 64 + j * 16 + col_l;
            float bias = bo[nn];
#pragma unroll
            for (int r = 0; r < 4; ++r) {
                int m = m0 + wr * 64 + i * 16 + rowg + r;
                out[(size_t)m * 256 + nn] = acc[i][j][r] + bias;
            }
        }
}

// ---------------------------------------------------------------------------
extern "C" void kernel_launch(void* const* d_in, const int* in_sizes, int n_in,
                              void* d_out, int out_size, void* d_ws, size_t ws_size,
                              hipStream_t stream) {
    const float* x      = (const float*)d_in[0];
    const float* sin_t  = (const float*)d_in[1];
    const float* cos_t  = (const float*)d_in[2];
    const float* mask_h = (const float*)d_in[3];
    const float* mask_w = (const float*)d_in[4];
    const float* Wq     = (const float*)d_in[5];
    const float* bq     = (const float*)d_in[6];
    const float* Wk     = (const float*)d_in[7];
    const float* bk     = (const float*)d_in[8];
    const float* Wv     = (const float*)d_in[9];
    const float* bv     = (const float*)d_in[10];
    const float* conv_w = (const float*)d_in[11];
    const float* conv_b = (const float*)d_in[12];
    const float* Wo     = (const float*)d_in[13];
    const float* bo     = (const float*)d_in[14];

    // ws (bf16 buffers)
    unsigned short* ws    = (unsigned short*)d_ws;
    unsigned short* v16   = ws;              // (B,H,W,C)
    unsigned short* lepe16= v16 + NEL;       // (B,H,W,C)
    unsigned short* qr16  = lepe16 + NEL;    // (B,NH,H,W,KD)
    unsigned short* kr16  = qr16 + NEL;
    unsigned short* y16   = kr16 + NEL;      // (B,H,W,C)
    unsigned short* Wt16  = y16 + NEL;       // (768,256) n-major (+Wo after)
    unsigned short* Wot16 = Wt16 + 768 * 256;// (256,256) n-major

    // d_out scratch: lower half = vv16 (bf16), upper half = x16 (bf16).
    unsigned short* vv16 = (unsigned short*)d_out;
    unsigned short* x16  = (unsigned short*)d_out + NEL;

    prep_all<<<8192 + 128, 256, 0, stream>>>(x, x16, Wq, Wk, Wv, Wo, Wt16);

    qkv_mfma<<<dim3(M_TOT / 128, 6), 256, 0, stream>>>(
        x16, Wt16, bq, bk, bv, sin_t, cos_t, qr16, kr16, v16);

    conv_kernel<<<(int)(NEL / 32 / 256), 256, 0, stream>>>(v16, conv_w, conv_b, lepe16);

    attn_mfma<0><<<B * H * NH, 256, 0, stream>>>(qr16, kr16, v16, mask_w, nullptr, vv16);

    attn_mfma<1><<<B * W * NH, 256, 0, stream>>>(qr16, kr16, vv16, mask_h, lepe16, y16);

    gemm_out_mfma<<<dim3(M_TOT / 128, 2), 256, 0, stream>>>(y16, Wot16, bo, (float*)d_out);
}